// Round 3
// baseline (74.276 us; speedup 1.0000x reference)
//
#include <hip/hip_runtime.h>

typedef __attribute__((ext_vector_type(8))) short short8;
typedef __attribute__((ext_vector_type(4))) float f32x4;
typedef __attribute__((ext_vector_type(4))) unsigned int u32x4;
typedef __attribute__((ext_vector_type(2))) unsigned int u32x2;

#define C_TOT 256
#define O_TOT 256
#define HW_   784
#define NT_   128

__device__ __forceinline__ unsigned short f2b(float f) {
    union { float f; unsigned int u; } cv; cv.f = f;
    unsigned int u = cv.u;
    u += 0x7fffu + ((u >> 16) & 1u);   // round-to-nearest-even
    return (unsigned short)(u >> 16);
}

// Pre-pass: net_w f32 -> bf16 (row-major [O][C]) into workspace.
__global__ __launch_bounds__(256)
void cvt_netw(const float* __restrict__ w, unsigned short* __restrict__ wb) {
    const int i = (blockIdx.x * 256 + threadIdx.x) * 4;
    f32x4 v = *reinterpret_cast<const f32x4*>(w + i);
    u32x2 p;
    p[0] = (unsigned int)f2b(v[0]) | ((unsigned int)f2b(v[1]) << 16);
    p[1] = (unsigned int)f2b(v[2]) | ((unsigned int)f2b(v[3]) << 16);
    *reinterpret_cast<u32x2*>(wb + i) = p;
}

// Fused temporal-shift depthwise conv (f32) + 1x1 conv via bf16 MFMA + bias.
// Block: one frame n x one 64-pixel tile. 4 waves, each 64(o) x 64(p).
__global__ __launch_bounds__(256, 2)
void msce_fused(const float* __restrict__ x,
                const float* __restrict__ w3,
                const float* __restrict__ w5,
                const float* __restrict__ w7,
                const unsigned short* __restrict__ net_wb,  // bf16, from pre-pass
                const float* __restrict__ net_b,
                float* __restrict__ out)                    // f32 output
{
    __shared__ float coefs[256][8];                    // [channel][dt+3]
    __shared__ __align__(16) unsigned int Bl[64 * 20]; // 64 pixel-rows x 80B

    const int tid  = threadIdx.x;
    const int wave = tid >> 6;
    const int lane = tid & 63;
    const int tile = blockIdx.x;   // 0..12
    const int n    = blockIdx.y;   // 0..127
    const int p0   = tile * 64;
    const int t    = n & 7;        // time index within segment

    // ---- per-channel temporal tap table (coef[dt+3], dt in [-3,3]) ----
    {
        const int c = tid;
        float cf[7];
        #pragma unroll
        for (int i = 0; i < 7; ++i) cf[i] = 0.f;
        if (c < 128) {
            #pragma unroll
            for (int i = 0; i < 3; ++i) cf[i + 2] = w3[c * 3 + i];
        } else if (c < 192) {
            #pragma unroll
            for (int i = 0; i < 5; ++i) cf[i + 1] = w5[(c - 128) * 5 + i];
        } else {
            #pragma unroll
            for (int i = 0; i < 7; ++i) cf[i] = w7[(c - 192) * 7 + i];
        }
        #pragma unroll
        for (int i = 0; i < 7; ++i) coefs[c][i] = cf[i];
        coefs[c][7] = 0.f;
    }

    // ---- acc init = bias (D layout: col=lane&15, row=(lane>>4)*4+r) ----
    f32x4 acc[4][4];
    {
        const int r0 = wave * 64 + (lane >> 4) * 4;
        #pragma unroll
        for (int ms = 0; ms < 4; ++ms) {
            float b[4];
            #pragma unroll
            for (int r = 0; r < 4; ++r) b[r] = net_b[r0 + ms * 16 + r];
            #pragma unroll
            for (int ns = 0; ns < 4; ++ns)
                #pragma unroll
                for (int r = 0; r < 4; ++r) acc[ms][ns][r] = b[r];
        }
    }

    const int cq = lane & 7;    // channel-in-octet (staging)
    const int pq = lane >> 3;   // pixel-octet
    const int pb = p0 + pq * 8; // pixel base (multiple of 8)
    const bool pvalid = pb < HW_;

    for (int kk = 0; kk < 8; ++kk) {
        __syncthreads();  // prev-iter B reads done; iter 0: coefs ready

        // ---- stage shifted tile y[32 ch][64 pix] in f32, pack to bf16 ----
        const int c = kk * 32 + wave * 8 + cq;
        float a8[8];
        #pragma unroll
        for (int e = 0; e < 8; ++e) a8[e] = 0.f;
        if (pvalid) {
            const float* rowp = x + (size_t)c * HW_ + pb;
            #pragma unroll
            for (int dt = -3; dt <= 3; ++dt) {
                const float cf = coefs[c][dt + 3];
                const int tt = t + dt;
                if (cf != 0.f && tt >= 0 && tt < 8) {   // wave-uniform in practice
                    const float* src = rowp + (size_t)(n + dt) * (C_TOT * HW_);
                    f32x4 u0 = *reinterpret_cast<const f32x4*>(src);
                    f32x4 u1 = *reinterpret_cast<const f32x4*>(src + 4);
                    #pragma unroll
                    for (int e = 0; e < 4; ++e) {
                        a8[e]     += cf * u0[e];
                        a8[e + 4] += cf * u1[e];
                    }
                }
            }
        }
        unsigned int v0, v1, v2, v3;
        v0 = (unsigned int)f2b(a8[0]) | ((unsigned int)f2b(a8[1]) << 16);
        v1 = (unsigned int)f2b(a8[2]) | ((unsigned int)f2b(a8[3]) << 16);
        v2 = (unsigned int)f2b(a8[4]) | ((unsigned int)f2b(a8[5]) << 16);
        v3 = (unsigned int)f2b(a8[6]) | ((unsigned int)f2b(a8[7]) << 16);

        // ---- 8x8 bf16 xor-butterfly transpose within 8-lane groups ----
        {
            unsigned int t0, t1, q0, q1;
            t0 = (cq & 4) ? v0 : v2;
            t1 = (cq & 4) ? v1 : v3;
            q0 = (unsigned int)__shfl_xor((int)t0, 4);
            q1 = (unsigned int)__shfl_xor((int)t1, 4);
            if (cq & 4) { v0 = q0; v1 = q1; } else { v2 = q0; v3 = q1; }
            t0 = (cq & 2) ? v0 : v1;
            t1 = (cq & 2) ? v2 : v3;
            q0 = (unsigned int)__shfl_xor((int)t0, 2);
            q1 = (unsigned int)__shfl_xor((int)t1, 2);
            if (cq & 2) { v0 = q0; v2 = q1; } else { v1 = q0; v3 = q1; }
            unsigned int s0 = (cq & 1) ? (v0 & 0xffffu) : (v0 >> 16);
            unsigned int s1 = (cq & 1) ? (v1 & 0xffffu) : (v1 >> 16);
            unsigned int s2 = (cq & 1) ? (v2 & 0xffffu) : (v2 >> 16);
            unsigned int s3 = (cq & 1) ? (v3 & 0xffffu) : (v3 >> 16);
            s0 = (unsigned int)__shfl_xor((int)s0, 1);
            s1 = (unsigned int)__shfl_xor((int)s1, 1);
            s2 = (unsigned int)__shfl_xor((int)s2, 1);
            s3 = (unsigned int)__shfl_xor((int)s3, 1);
            if (cq & 1) {
                v0 = (v0 & 0xffff0000u) | s0;
                v1 = (v1 & 0xffff0000u) | s1;
                v2 = (v2 & 0xffff0000u) | s2;
                v3 = (v3 & 0xffff0000u) | s3;
            } else {
                v0 = (v0 & 0xffffu) | (s0 << 16);
                v1 = (v1 & 0xffffu) | (s1 << 16);
                v2 = (v2 & 0xffffu) | (s2 << 16);
                v3 = (v3 & 0xffffu) | (s3 << 16);
            }
        }
        // lane holds pixel p0+lane, channels [kk*32+wave*8 .. +8)
        {
            u32x4 w4;
            w4[0] = v0; w4[1] = v1; w4[2] = v2; w4[3] = v3;
            *reinterpret_cast<u32x4*>(&Bl[lane * 20 + wave * 4]) = w4;
        }
        __syncthreads();

        // ---- MFMA: A = net_w (bf16, L2-resident), B from LDS ----
        short8 af[4];
        const int arow = wave * 64 + (lane & 15);
        const int acol = kk * 32 + (lane >> 4) * 8;
        #pragma unroll
        for (int ms = 0; ms < 4; ++ms)
            af[ms] = *reinterpret_cast<const short8*>(
                         &net_wb[(size_t)(arow + ms * 16) * C_TOT + acol]);
        short8 bfr[4];
        #pragma unroll
        for (int ns = 0; ns < 4; ++ns) {
            u32x4 bw = *reinterpret_cast<const u32x4*>(
                           &Bl[(ns * 16 + (lane & 15)) * 20 + (lane >> 4) * 4]);
            bfr[ns] = __builtin_bit_cast(short8, bw);
        }
        #pragma unroll
        for (int ms = 0; ms < 4; ++ms)
            #pragma unroll
            for (int ns = 0; ns < 4; ++ns)
                acc[ms][ns] = __builtin_amdgcn_mfma_f32_16x16x32_bf16(
                                  af[ms], bfr[ns], acc[ms][ns], 0, 0, 0);
    }

    // ---- store: out[n][o][p], f32 ----
    const int prow = lane & 15;
    const int kg   = lane >> 4;
    #pragma unroll
    for (int ns = 0; ns < 4; ++ns) {
        const int p = p0 + ns * 16 + prow;
        if (p < HW_) {
            #pragma unroll
            for (int ms = 0; ms < 4; ++ms) {
                const int o = wave * 64 + ms * 16 + kg * 4;
                const size_t base = ((size_t)n * O_TOT + o) * HW_ + p;
                #pragma unroll
                for (int r = 0; r < 4; ++r)
                    out[base + (size_t)r * HW_] = acc[ms][ns][r];
            }
        }
    }
}

extern "C" void kernel_launch(void* const* d_in, const int* in_sizes, int n_in,
                              void* d_out, int out_size, void* d_ws, size_t ws_size,
                              hipStream_t stream) {
    const float* x    = (const float*)d_in[0];
    const float* w3p  = (const float*)d_in[1];
    const float* w5p  = (const float*)d_in[2];
    const float* w7p  = (const float*)d_in[3];
    const float* netw = (const float*)d_in[4];
    const float* netb = (const float*)d_in[5];
    float* outp = (float*)d_out;
    unsigned short* netwb = (unsigned short*)d_ws;   // 128 KB bf16 net_w

    hipLaunchKernelGGL(cvt_netw, dim3(64), dim3(256), 0, stream, netw, netwb);

    dim3 grid(13, 128);   // 13 pixel-tiles x 128 frames
    hipLaunchKernelGGL(msce_fused, grid, dim3(256), 0, stream,
                       x, w3p, w5p, w7p, netwb, netb, outp);
}

// Round 4
// 70.097 us; speedup vs baseline: 1.0596x; 1.0596x over previous
//
#include <hip/hip_runtime.h>

typedef __attribute__((ext_vector_type(8))) short short8;
typedef __attribute__((ext_vector_type(4))) float f32x4;
typedef __attribute__((ext_vector_type(4))) unsigned int u32x4;

#define C_TOT 256
#define O_TOT 256
#define HW_   784
#define KMAX  1792   // max folded-K entries (256 ch x 7 taps)

// ws layout (bytes):
//   meta  u32[4]        @ 0
//   idx   u32[KMAX]     @ 16            (c | dtm<<8), dtm = dt+3 in [0,6]
//   cval  f32[KMAX]     @ 16 + 4*KMAX
//   A2    bf16[256*Kpad]@ 16 + 8*KMAX   (row-major, row length Kpad)
#define WS_IDX_OFF  16
#define WS_CVAL_OFF (16 + 4 * KMAX)
#define WS_A2_OFF   (16 + 8 * KMAX)

__device__ __forceinline__ unsigned short f2b(float f) {
    union { float f; unsigned int u; } cv; cv.f = f;
    unsigned int u = cv.u;
    u += 0x7fffu + ((u >> 16) & 1u);   // round-to-nearest-even
    return (unsigned short)(u >> 16);
}

// ---- pre-pass 1: enumerate nonzero taps (c,dt) in (c,dt) order ----
__global__ __launch_bounds__(256)
void build_idx(const float* __restrict__ w3, const float* __restrict__ w5,
               const float* __restrict__ w7, unsigned int* __restrict__ meta,
               unsigned int* __restrict__ idx, float* __restrict__ cval)
{
    const int c = threadIdx.x;
    float cf[7];
    #pragma unroll
    for (int i = 0; i < 7; ++i) cf[i] = 0.f;
    if (c < 128) {
        #pragma unroll
        for (int i = 0; i < 3; ++i) cf[i + 2] = w3[c * 3 + i];
    } else if (c < 192) {
        #pragma unroll
        for (int i = 0; i < 5; ++i) cf[i + 1] = w5[(c - 128) * 5 + i];
    } else {
        #pragma unroll
        for (int i = 0; i < 7; ++i) cf[i] = w7[(c - 192) * 7 + i];
    }
    int cnt = 0;
    #pragma unroll
    for (int i = 0; i < 7; ++i) cnt += (cf[i] != 0.f);

    __shared__ int sc[256];
    sc[c] = cnt;
    __syncthreads();
    for (int off = 1; off < 256; off <<= 1) {   // inclusive scan
        int u = 0;
        if (c >= off) u = sc[c - off];
        __syncthreads();
        sc[c] += u;
        __syncthreads();
    }
    const int end   = sc[c];
    const int start = end - cnt;
    int J = sc[255];
    if (J > KMAX) J = KMAX;
    int Kpad = (J + 31) & ~31;
    if (Kpad > KMAX) Kpad = KMAX;
    if (c == 0) { meta[0] = (unsigned int)Kpad; meta[1] = (unsigned int)J; }

    int j = start;
    #pragma unroll
    for (int i = 0; i < 7; ++i) {
        if (cf[i] != 0.f) {
            if (j < KMAX) { idx[j] = (unsigned int)c | ((unsigned int)i << 8); cval[j] = cf[i]; }
            ++j;
        }
    }
    for (int p = J + c; p < Kpad; p += 256) {   // pad: zero-coef, always-valid frame
        idx[p] = 0u | (3u << 8);
        cval[p] = 0.f;
    }
}

// ---- pre-pass 2: A2[o][j] = net_w[o][c_j] * cval[j], bf16 ----
__global__ __launch_bounds__(256)
void build_A2(const float* __restrict__ netw, const unsigned int* __restrict__ meta,
              const unsigned int* __restrict__ idx, const float* __restrict__ cval,
              unsigned short* __restrict__ A2)
{
    const int o = blockIdx.x;
    const int Kpad = (int)meta[0];
    for (int j = threadIdx.x; j < Kpad; j += 256) {
        const int c = (int)(idx[j] & 255u);
        A2[(size_t)o * Kpad + j] = f2b(netw[o * C_TOT + c] * cval[j]);
    }
}

// ---- fused: gathered-K GEMM out[n] = A2 @ xgather + b ----
// Block: one frame n x one 64-pixel tile. 4 waves, each 64(o) x 64(p).
// Pipelined: one barrier per K-step, double-buffered B tile in LDS.
__global__ __launch_bounds__(256, 3)
void msce_fused(const float* __restrict__ x,
                const unsigned short* __restrict__ A2,
                const unsigned int* __restrict__ gidx,
                const unsigned int* __restrict__ meta,
                const float* __restrict__ net_b,
                float* __restrict__ out)
{
    __shared__ unsigned int s_idx[KMAX];
    __shared__ __align__(16) unsigned int Bl[2][64 * 20];  // 2 x (64 rows x 80B)

    const int tid  = threadIdx.x;
    const int wave = tid >> 6;
    const int lane = tid & 63;
    const int tile = blockIdx.x;   // 0..12
    const int n    = blockIdx.y;   // 0..127
    const int p0   = tile * 64;
    const int t    = n & 7;        // time index within segment

    const int Kpad = (int)meta[0];
    const int KK   = Kpad >> 5;

    // cooperative idx -> LDS
    for (int i = tid; i < Kpad; i += 256) s_idx[i] = gidx[i];

    // acc init = bias (D layout: col=lane&15, row=(lane>>4)*4+r)
    f32x4 acc[4][4];
    {
        const int r0 = wave * 64 + (lane >> 4) * 4;
        #pragma unroll
        for (int ms = 0; ms < 4; ++ms) {
            float b[4];
            #pragma unroll
            for (int r = 0; r < 4; ++r) b[r] = net_b[r0 + ms * 16 + r];
            #pragma unroll
            for (int ns = 0; ns < 4; ++ns)
                #pragma unroll
                for (int r = 0; r < 4; ++r) acc[ms][ns][r] = b[r];
        }
    }

    const int cq = lane & 7;    // k-in-octet (staging)
    const int pq = lane >> 3;   // pixel-octet
    const int pb = p0 + pq * 8; // pixel base (multiple of 8)
    const bool pvalid = pb < HW_;

    __syncthreads();            // s_idx ready

    // stage-load for K-step kk into registers (no weighting: folded into A2)
    auto issue_x = [&](int kk, f32x4& u0, f32x4& u1) {
        const unsigned int e = s_idx[kk * 32 + wave * 8 + cq];
        const int c   = (int)(e & 255u);
        const int dtm = (int)((e >> 8) & 7u);
        const int tt  = t + dtm - 3;
        const bool v  = pvalid && (tt >= 0) && (tt < 8);
        u0 = (f32x4)0.f; u1 = (f32x4)0.f;
        if (v) {
            const float* src = x + ((size_t)(n + dtm - 3) * C_TOT + c) * HW_ + pb;
            u0 = *reinterpret_cast<const f32x4*>(src);
            u1 = *reinterpret_cast<const f32x4*>(src + 4);
        }
    };

    f32x4 cu0, cu1;
    issue_x(0, cu0, cu1);

    const int arow = wave * 64 + (lane & 15);

    for (int kk = 0; kk < KK; ++kk) {
        // ---- pack current K-step to bf16 ----
        unsigned int v0, v1, v2, v3;
        v0 = (unsigned int)f2b(cu0[0]) | ((unsigned int)f2b(cu0[1]) << 16);
        v1 = (unsigned int)f2b(cu0[2]) | ((unsigned int)f2b(cu0[3]) << 16);
        v2 = (unsigned int)f2b(cu1[0]) | ((unsigned int)f2b(cu1[1]) << 16);
        v3 = (unsigned int)f2b(cu1[2]) | ((unsigned int)f2b(cu1[3]) << 16);

        // ---- 8x8 bf16 xor-butterfly transpose within 8-lane groups ----
        {
            unsigned int t0, t1, q0, q1;
            t0 = (cq & 4) ? v0 : v2;
            t1 = (cq & 4) ? v1 : v3;
            q0 = (unsigned int)__shfl_xor((int)t0, 4);
            q1 = (unsigned int)__shfl_xor((int)t1, 4);
            if (cq & 4) { v0 = q0; v1 = q1; } else { v2 = q0; v3 = q1; }
            t0 = (cq & 2) ? v0 : v1;
            t1 = (cq & 2) ? v2 : v3;
            q0 = (unsigned int)__shfl_xor((int)t0, 2);
            q1 = (unsigned int)__shfl_xor((int)t1, 2);
            if (cq & 2) { v0 = q0; v2 = q1; } else { v1 = q0; v3 = q1; }
            unsigned int s0 = (cq & 1) ? (v0 & 0xffffu) : (v0 >> 16);
            unsigned int s1 = (cq & 1) ? (v1 & 0xffffu) : (v1 >> 16);
            unsigned int s2 = (cq & 1) ? (v2 & 0xffffu) : (v2 >> 16);
            unsigned int s3 = (cq & 1) ? (v3 & 0xffffu) : (v3 >> 16);
            s0 = (unsigned int)__shfl_xor((int)s0, 1);
            s1 = (unsigned int)__shfl_xor((int)s1, 1);
            s2 = (unsigned int)__shfl_xor((int)s2, 1);
            s3 = (unsigned int)__shfl_xor((int)s3, 1);
            if (cq & 1) {
                v0 = (v0 & 0xffff0000u) | s0;
                v1 = (v1 & 0xffff0000u) | s1;
                v2 = (v2 & 0xffff0000u) | s2;
                v3 = (v3 & 0xffff0000u) | s3;
            } else {
                v0 = (v0 & 0xffffu) | (s0 << 16);
                v1 = (v1 & 0xffffu) | (s1 << 16);
                v2 = (v2 & 0xffffu) | (s2 << 16);
                v3 = (v3 & 0xffffu) | (s3 << 16);
            }
        }
        // lane holds pixel p0+lane, k-slots [kk*32+wave*8 .. +8)
        {
            u32x4 w4;
            w4[0] = v0; w4[1] = v1; w4[2] = v2; w4[3] = v3;
            *reinterpret_cast<u32x4*>(&Bl[kk & 1][lane * 20 + wave * 4]) = w4;
        }

        // ---- prefetch next K-step's x data (overlaps barrier+MFMA) ----
        f32x4 nu0, nu1;
        if (kk + 1 < KK) issue_x(kk + 1, nu0, nu1);
        else { nu0 = (f32x4)0.f; nu1 = (f32x4)0.f; }

        // ---- A-fragments for this K-step (L2-resident) ----
        short8 af[4];
        const int acol = kk * 32 + (lane >> 4) * 8;
        #pragma unroll
        for (int ms = 0; ms < 4; ++ms)
            af[ms] = *reinterpret_cast<const short8*>(
                         &A2[(size_t)(arow + ms * 16) * Kpad + acol]);

        __syncthreads();   // B tile ready

        short8 bfr[4];
        #pragma unroll
        for (int ns = 0; ns < 4; ++ns) {
            u32x4 bw = *reinterpret_cast<const u32x4*>(
                           &Bl[kk & 1][(ns * 16 + (lane & 15)) * 20 + (lane >> 4) * 4]);
            bfr[ns] = __builtin_bit_cast(short8, bw);
        }
        #pragma unroll
        for (int ms = 0; ms < 4; ++ms)
            #pragma unroll
            for (int ns = 0; ns < 4; ++ns)
                acc[ms][ns] = __builtin_amdgcn_mfma_f32_16x16x32_bf16(
                                  af[ms], bfr[ns], acc[ms][ns], 0, 0, 0);

        cu0 = nu0; cu1 = nu1;
    }

    // ---- store: out[n][o][p], f32 ----
    const int prow = lane & 15;
    const int kg   = lane >> 4;
    #pragma unroll
    for (int ns = 0; ns < 4; ++ns) {
        const int p = p0 + ns * 16 + prow;
        if (p < HW_) {
            #pragma unroll
            for (int ms = 0; ms < 4; ++ms) {
                const int o = wave * 64 + ms * 16 + kg * 4;
                const size_t base = ((size_t)n * O_TOT + o) * HW_ + p;
                #pragma unroll
                for (int r = 0; r < 4; ++r)
                    out[base + (size_t)r * HW_] = acc[ms][ns][r];
            }
        }
    }
}

extern "C" void kernel_launch(void* const* d_in, const int* in_sizes, int n_in,
                              void* d_out, int out_size, void* d_ws, size_t ws_size,
                              hipStream_t stream) {
    const float* x    = (const float*)d_in[0];
    const float* w3p  = (const float*)d_in[1];
    const float* w5p  = (const float*)d_in[2];
    const float* w7p  = (const float*)d_in[3];
    const float* netw = (const float*)d_in[4];
    const float* netb = (const float*)d_in[5];
    float* outp = (float*)d_out;

    char* ws = (char*)d_ws;
    unsigned int*   meta = (unsigned int*)ws;
    unsigned int*   idx  = (unsigned int*)(ws + WS_IDX_OFF);
    float*          cval = (float*)(ws + WS_CVAL_OFF);
    unsigned short* A2   = (unsigned short*)(ws + WS_A2_OFF);

    hipLaunchKernelGGL(build_idx, dim3(1), dim3(256), 0, stream,
                       w3p, w5p, w7p, meta, idx, cval);
    hipLaunchKernelGGL(build_A2, dim3(256), dim3(256), 0, stream,
                       netw, meta, idx, cval, A2);

    dim3 grid(13, 128);   // 13 pixel-tiles x 128 frames
    hipLaunchKernelGGL(msce_fused, grid, dim3(256), 0, stream,
                       x, A2, idx, meta, netb, outp);
}